// Round 7
// baseline (781.203 us; speedup 1.0000x reference)
//
#include <hip/hip_runtime.h>
#include <cstdint>
#include <cstddef>

// dec: [16, 3999, 512] fp32, wgt: [16, 512] fp32, out: [16, 32000] fp32
//   est[f][w] = dot(dec[f], wgt[w]);  out[8g+i] = est[g][i] + est[g-1][8+i]
//
// R13 = R12 (coalesced lane remap) with the register budget engineered to
// fit: R12 spilled its acc[4][16]+wv[8] to scratch (WRITE_SIZE 505 MB on a
// 2 MB output, VGPR=84 vs ~125 needed) and ran 620 us. This version:
//   - 512-thread blocks (8 waves, 64 slots): each 16-lane group owns p=2
//     slots -> acc[2][16] = 32 VGPRs.
//   - wv[4] inner weight block (4 steps of 4 rows) = 16 VGPRs.
//   - xv[2][2] two-deep prefetch = 8 VGPRs (~32 KB/CU in flight >> 9 KB
//     BW-delay product).  Total ~80 VGPR < 128 cap of launch_bounds(512,4).
// Lane remap: kappa=lane&15 reads a 16 B stripe; each 16-lane group covers
// 256 B contiguous of one frame -> every wave-instr = 16 fully-consumed
// lines (R12 measured 2.5 TB/s even while scratch-thrashing, vs 2.2 TB/s
// for the old lane=frame scatter). Weights from LDS (kappa-dependent);
// kappa-split partials reduced by 4-step __shfl_xor butterfly. Zero
// main-loop barriers.

#define NBC     16
#define FRAMES  3999
#define EE      512
#define TOUT    32000
#define NGROUP  4000
#define GPB     63      // output groups per block (64 frame-slots)
#define RSTR    65      // red row stride (pad)

__global__ __launch_bounds__(512, 4) void decoder_kernel(
    const float* __restrict__ dec,
    const float* __restrict__ wgt,
    float* __restrict__ out)
{
    __shared__ __align__(16) float wl[16 * EE];   // 32 KB weights
    __shared__ float red[16 * RSTR];              // est[w][slot], padded

    const int tid   = threadIdx.x;
    const int bc    = blockIdx.y;        // 0..15
    const int chunk = blockIdx.x;        // 0..63
    const int g0    = chunk * GPB;

    const int lane  = tid & 63;
    const int h     = tid >> 6;          // wave 0..7
    const int kappa = lane & 15;         // k-phase within frame
    const int fg    = lane >> 4;         // frame sub-group 0..3

    // ---- stage weights into LDS (coalesced, once) ----
    {
        const float4* ws = (const float4*)wgt;
        float4*       wd = (float4*)wl;
        #pragma unroll
        for (int i = 0; i < 4; ++i)
            wd[tid + 512 * i] = ws[tid + 512 * i];
    }
    __syncthreads();

    // ---- this wave's 8 slots: slot = h*8 + p*4 + fg, p = 0..1 ----
    const float* decb = dec + (size_t)bc * FRAMES * EE;
    int   slot0, slot1;
    float msk0, msk1;
    const float* xp0;
    const float* xp1;
    {
        slot0 = h * 8 + fg;
        slot1 = h * 8 + 4 + fg;
        const int f0 = g0 - 1 + slot0;
        const int f1 = g0 - 1 + slot1;
        msk0 = (f0 >= 0 && f0 < FRAMES) ? 1.0f : 0.0f;
        msk1 = (f1 >= 0 && f1 < FRAMES) ? 1.0f : 0.0f;
        const int fr0 = min(max(f0, 0), FRAMES - 1);
        const int fr1 = min(max(f1, 0), FRAMES - 1);
        xp0 = decb + (size_t)fr0 * EE + kappa * 4;   // 16 B stripe
        xp1 = decb + (size_t)fr1 * EE + kappa * 4;
    }

    float acc[2][16];
    #pragma unroll
    for (int w = 0; w < 16; ++w) { acc[0][w] = 0.f; acc[1][w] = 0.f; }

    // ---- main loop: u = k-block of 64 floats; 2-deep prefetch; no barriers
    float4 xv[2][2];
    xv[0][0] = *(const float4*)(xp0);
    xv[0][1] = *(const float4*)(xp1);

    #pragma unroll
    for (int u = 0; u < 8; ++u) {
        const int cur = u & 1;           // compile-time after unroll
        if (u < 7) {
            xv[cur ^ 1][0] = *(const float4*)(xp0 + (u + 1) * 64);
            xv[cur ^ 1][1] = *(const float4*)(xp1 + (u + 1) * 64);
        }
        #pragma unroll
        for (int wq = 0; wq < 4; ++wq) {
            float4 wv[4];
            #pragma unroll
            for (int w4 = 0; w4 < 4; ++w4)
                wv[w4] = *(const float4*)(wl + (wq * 4 + w4) * EE
                                             + u * 64 + kappa * 4);
            #pragma unroll
            for (int w4 = 0; w4 < 4; ++w4) {
                acc[0][wq * 4 + w4] += xv[cur][0].x * wv[w4].x
                                     + xv[cur][0].y * wv[w4].y
                                     + xv[cur][0].z * wv[w4].z
                                     + xv[cur][0].w * wv[w4].w;
                acc[1][wq * 4 + w4] += xv[cur][1].x * wv[w4].x
                                     + xv[cur][1].y * wv[w4].y
                                     + xv[cur][1].z * wv[w4].z
                                     + xv[cur][1].w * wv[w4].w;
            }
        }
    }

    // ---- reduce over the 16 kappa-lanes; lane kappa==w writes est ----
    #pragma unroll
    for (int p = 0; p < 2; ++p) {
        const int   sl = p ? slot1 : slot0;
        const float mk = p ? msk1  : msk0;
        #pragma unroll
        for (int w = 0; w < 16; ++w) {
            float v = acc[p][w];
            v += __shfl_xor(v, 1);
            v += __shfl_xor(v, 2);
            v += __shfl_xor(v, 4);
            v += __shfl_xor(v, 8);
            if (kappa == w)                       // 4 lanes (one per fg)
                red[w * RSTR + sl] = v * mk;
        }
    }
    __syncthreads();

    // ---- fused overlap-add: 504 outputs, 512 threads -> 1 iteration ----
    if (tid < GPB * 8) {
        const int j = tid >> 3;          // group offset in block, 0..62
        const int i = tid & 7;           // sample within group
        const int g = g0 + j;
        if (g < NGROUP)
            out[(size_t)bc * TOUT + g * 8 + i]
                = red[i * RSTR + (j + 1)]        // est[g][i]
                + red[(8 + i) * RSTR + j];       // est[g-1][8+i]
    }
}

extern "C" void kernel_launch(void* const* d_in, const int* in_sizes, int n_in,
                              void* d_out, int out_size, void* d_ws, size_t ws_size,
                              hipStream_t stream) {
    const float* dec = (const float*)d_in[0];   // [8,2,3999,512] fp32
    const float* wgt = (const float*)d_in[1];   // [16,512] fp32
    float* out = (float*)d_out;                 // [8,2,32000] fp32

    decoder_kernel<<<dim3(64, 16), dim3(512), 0, stream>>>(dec, wgt, out);
}